// Round 6
// baseline (706.932 us; speedup 1.0000x reference)
//
#include <hip/hip_runtime.h>
#include <hip/hip_bf16.h>

// NeuralODE RK4, bf16 MFMA persistent kernel, swapped-operand layout.
// BS=1024, ZDIM=HID=256, TLEN=128 -> 127 steps x 4 stages = 508 f-evals.
//
// Only 64 WGs exist (BS/16 row-tiles) -> at most 64 of 256 CUs busy; total
// time = per-WG stage latency x 508. The dominant stage term is the LDS
// broadcast read (every wave reads the full 8KB state tile per GEMM), which
// scales with waves/WG. This revision: 4 waves x 64 cols/wave (256 thr,
// 1 wave/SIMD) instead of 8 x 32. Halves LDS reads (128->64 b128/stage),
// doubles MFMA:read ratio to 4:1, keeps ALL waves active in every phase
// (unlike the failed role-split, which idled half the waves). Weights are
// 256 VGPR/wave; __launch_bounds__(256,1) gives the 512-VGPR budget.
//
// Swapped trick: S^T = W^T @ z^T (weights as MFMA A-operand). C/D layout:
// col(lane&15) = batch row m, row(q*4+r) = output col c. LDS round-trip is
// per-m contiguous: packed b64 writes, b128 frag reads, row stride 264 u16.
//
// Rotated k-slice order ks=(2wv+i)&7 spreads the post-barrier LDS queue.
// Weight frags stored PRE-ROTATED at load time so all hot-loop register
// indices are compile-time static (R4: runtime-indexed frags -> scratch,
// 6.6x slowdown).

#define BS   1024
#define ZDIM 256
#define TLEN 128
#define ROWSTRIDE 264   // u16 units; 528 B = 16B-aligned, odd multiple of 4 units

typedef short v8s __attribute__((ext_vector_type(8)));
typedef float v4f __attribute__((ext_vector_type(4)));

static __device__ __forceinline__ ushort f2bf_rne(float x) {
    union { float f; unsigned u; } v; v.f = x;
    unsigned r = v.u + 0x7FFFu + ((v.u >> 16) & 1u);
    return (ushort)(r >> 16);
}

static __device__ __forceinline__ unsigned pk2(float a, float b) {
    union { __hip_bfloat162 h; unsigned u; } cv;
    cv.h = __float22bfloat162_rn(make_float2(a, b));
    return cv.u;
}

static __device__ __forceinline__ float fast_tanh(float x) {
    // tanh(x) = 1 - 2/(exp2(2x*log2e)+1); v_exp + v_rcp, no slow libm div
    float e = __builtin_amdgcn_exp2f(2.88539008177793f * x);
    float r = __builtin_amdgcn_rcpf(e + 1.0f);
    return 1.0f - 2.0f * r;
}

__global__ __launch_bounds__(256, 1)
void ode_mfma_kernel(const float* __restrict__ z0,
                     const float* __restrict__ t,
                     const float* __restrict__ W1,
                     const float* __restrict__ b1,
                     const float* __restrict__ W2,
                     const float* __restrict__ b2,
                     float* __restrict__ out)
{
    // state buffers, swapped layout: buf[m][c] bf16, row stride ROWSTRIDE
    __shared__ ushort zbuf[16 * ROWSTRIDE];
    __shared__ ushort hbuf[16 * ROWSTRIDE];
    __shared__ float  hsh[TLEN];            // per-step h = t[s+1]-t[s]

    const int tid  = threadIdx.x;
    const int wv   = tid >> 6;        // 0..3
    const int lane = tid & 63;
    const int q    = lane >> 4;       // 0..3
    const int ln   = lane & 15;       // = batch row m (within tile)
    const int rowbase = blockIdx.x * 16;

    if (tid < TLEN - 1) hsh[tid] = t[tid + 1] - t[tid];

    // ---- one-time: weights -> registers, A-frag layout, PRE-ROTATED ----
    // wf[ct][i] holds k-slice ks=(2wv+i)&7:
    //   lane has W[k=32ks+8q+j][c = 64wv + 16ct + ln]
    v8s w1f[4][8], w2f[4][8];
    #pragma unroll
    for (int ct = 0; ct < 4; ++ct) {
        const int c = wv * 64 + ct * 16 + ln;
        #pragma unroll
        for (int i = 0; i < 8; ++i) {
            const int ks = (2 * wv + i) & 7;
            v8s a, b;
            #pragma unroll
            for (int j = 0; j < 8; ++j) {
                const int k = ks * 32 + q * 8 + j;
                a[j] = (short)f2bf_rne(W1[k * ZDIM + c]);
                b[j] = (short)f2bf_rne(W2[k * ZDIM + c]);
            }
            w1f[ct][i] = a;
            w2f[ct][i] = b;
        }
    }

    // biases in C'-layout: value row (c = 64wv + 16ct + 4q + r)
    v4f b1f[4], b2f[4];
    #pragma unroll
    for (int ct = 0; ct < 4; ++ct)
        #pragma unroll
        for (int r = 0; r < 4; ++r) {
            b1f[ct][r] = b1[wv * 64 + ct * 16 + q * 4 + r];
            b2f[ct][r] = b2[wv * 64 + ct * 16 + q * 4 + r];
        }

    // LDS offsets (u16 units); rdaddr[i] carries the matching slice rotation
    const int rdbase = ln * ROWSTRIDE + q * 8;            // + 32*ks, b128 reads
    const int wrbase = ln * ROWSTRIDE + wv * 64 + q * 4;  // + 16*ct,  b64 writes
    int rdaddr[8];
    #pragma unroll
    for (int i = 0; i < 8; ++i)
        rdaddr[i] = rdbase + ((2 * wv + i) & 7) * 32;

    // ---- initial state ----
    float zloc[4][4];   // z[m=ln][c = 64wv+16ct+4q+r], fp32
    #pragma unroll
    for (int ct = 0; ct < 4; ++ct) {
        #pragma unroll
        for (int r = 0; r < 4; ++r)
            zloc[ct][r] = z0[(rowbase + ln) * ZDIM + wv * 64 + ct * 16 + q * 4 + r];
        uint2 p; p.x = pk2(zloc[ct][0], zloc[ct][1]); p.y = pk2(zloc[ct][2], zloc[ct][3]);
        *(uint2*)&zbuf[wrbase + ct * 16] = p;
    }
    __syncthreads();

    float kacc[4][4];

    #pragma unroll 1
    for (int step = 0; step < TLEN - 1; ++step) {
        const float h = hsh[step];

        #pragma unroll
        for (int stage = 0; stage < 4; ++stage) {
            // ---- GEMM1: S^T = W1^T z^T + b1 (4 MFMAs per b128 read) ----
            v4f a0 = b1f[0], a1 = b1f[1], a2 = b1f[2], a3 = b1f[3];
            #pragma unroll
            for (int i = 0; i < 8; ++i) {
                const v8s zf = *(const v8s*)&zbuf[rdaddr[i]];
                a0 = __builtin_amdgcn_mfma_f32_16x16x32_bf16(w1f[0][i], zf, a0, 0, 0, 0);
                a1 = __builtin_amdgcn_mfma_f32_16x16x32_bf16(w1f[1][i], zf, a1, 0, 0, 0);
                a2 = __builtin_amdgcn_mfma_f32_16x16x32_bf16(w1f[2][i], zf, a2, 0, 0, 0);
                a3 = __builtin_amdgcn_mfma_f32_16x16x32_bf16(w1f[3][i], zf, a3, 0, 0, 0);
            }
            // tanh -> hbuf; write each ct as soon as it's packed
            {
                uint2 p;
                p.x = pk2(fast_tanh(a0[0]), fast_tanh(a0[1]));
                p.y = pk2(fast_tanh(a0[2]), fast_tanh(a0[3]));
                *(uint2*)&hbuf[wrbase] = p;
                p.x = pk2(fast_tanh(a1[0]), fast_tanh(a1[1]));
                p.y = pk2(fast_tanh(a1[2]), fast_tanh(a1[3]));
                *(uint2*)&hbuf[wrbase + 16] = p;
                p.x = pk2(fast_tanh(a2[0]), fast_tanh(a2[1]));
                p.y = pk2(fast_tanh(a2[2]), fast_tanh(a2[3]));
                *(uint2*)&hbuf[wrbase + 32] = p;
                p.x = pk2(fast_tanh(a3[0]), fast_tanh(a3[1]));
                p.y = pk2(fast_tanh(a3[2]), fast_tanh(a3[3]));
                *(uint2*)&hbuf[wrbase + 48] = p;
            }
            __syncthreads();

            // ---- GEMM2: f^T = W2^T h^T + b2 ----
            v4f f0 = b2f[0], f1 = b2f[1], f2 = b2f[2], f3 = b2f[3];
            #pragma unroll
            for (int i = 0; i < 8; ++i) {
                const v8s hf = *(const v8s*)&hbuf[rdaddr[i]];
                f0 = __builtin_amdgcn_mfma_f32_16x16x32_bf16(w2f[0][i], hf, f0, 0, 0, 0);
                f1 = __builtin_amdgcn_mfma_f32_16x16x32_bf16(w2f[1][i], hf, f1, 0, 0, 0);
                f2 = __builtin_amdgcn_mfma_f32_16x16x32_bf16(w2f[2][i], hf, f2, 0, 0, 0);
                f3 = __builtin_amdgcn_mfma_f32_16x16x32_bf16(w2f[3][i], hf, f3, 0, 0, 0);
            }
            v4f fa[4] = { f0, f1, f2, f3 };

            // ---- RK4 epilogue: only zn pack+write before the barrier ----
            if (stage < 3) {
                const float c = (stage == 2) ? h : 0.5f * h;
                #pragma unroll
                for (int ct = 0; ct < 4; ++ct) {
                    float zn[4];
                    #pragma unroll
                    for (int r = 0; r < 4; ++r) zn[r] = zloc[ct][r] + c * fa[ct][r];
                    uint2 p; p.x = pk2(zn[0], zn[1]); p.y = pk2(zn[2], zn[3]);
                    *(uint2*)&zbuf[wrbase + ct * 16] = p;
                }
                __syncthreads();
                // deferred kacc bookkeeping: overlaps next GEMM1's reads
                #pragma unroll
                for (int ct = 0; ct < 4; ++ct)
                    #pragma unroll
                    for (int r = 0; r < 4; ++r) {
                        if (stage == 0) kacc[ct][r] = fa[ct][r];
                        else            kacc[ct][r] += 2.0f * fa[ct][r];
                    }
            } else {
                #pragma unroll
                for (int ct = 0; ct < 4; ++ct) {
                    #pragma unroll
                    for (int r = 0; r < 4; ++r) {
                        kacc[ct][r] += fa[ct][r];
                        zloc[ct][r] += (h * (1.0f / 6.0f)) * kacc[ct][r];
                    }
                    uint2 p; p.x = pk2(zloc[ct][0], zloc[ct][1]);
                    p.y = pk2(zloc[ct][2], zloc[ct][3]);
                    *(uint2*)&zbuf[wrbase + ct * 16] = p;
                }
                __syncthreads();
            }
        }
    }

    // ---- final store (one-time, uncoalesced is fine) ----
    #pragma unroll
    for (int ct = 0; ct < 4; ++ct)
        #pragma unroll
        for (int r = 0; r < 4; ++r)
            out[(rowbase + ln) * ZDIM + wv * 64 + ct * 16 + q * 4 + r] = zloc[ct][r];
}

extern "C" void kernel_launch(void* const* d_in, const int* in_sizes, int n_in,
                              void* d_out, int out_size, void* d_ws, size_t ws_size,
                              hipStream_t stream) {
    const float* z0 = (const float*)d_in[0];
    const float* t  = (const float*)d_in[1];
    const float* W1 = (const float*)d_in[2];
    const float* b1 = (const float*)d_in[3];
    const float* W2 = (const float*)d_in[4];
    const float* b2 = (const float*)d_in[5];
    float* out = (float*)d_out;

    dim3 grid(BS / 16);    // 64 workgroups, 16 batch rows each
    dim3 block(256);       // 4 waves, 1 per SIMD, 64 cols each
    hipLaunchKernelGGL(ode_mfma_kernel, grid, block, 0, stream,
                       z0, t, W1, b1, W2, b2, out);
}

// Round 7
// 582.120 us; speedup vs baseline: 1.2144x; 1.2144x over previous
//
#include <hip/hip_runtime.h>
#include <hip/hip_bf16.h>

// NeuralODE RK4, bf16 MFMA persistent kernel, swapped-operand layout.
// BS=1024, ZDIM=HID=256, TLEN=128 -> 127 steps x 4 stages = 508 f-evals.
//
// Structure locked by measurement:
//  - 8 waves/WG, 2/SIMD (R1 role-split and R6 4-wave both regressed ~30%:
//    1 active wave/SIMD exposes ~1900 cyc/stage of latency).
//  - Per-wave LDS reads pinned at 8 b128/GEMM (K=256, B-frag), so reads/CU
//    = 128/stage regardless of col split. That pipe is the floor (~1536cy).
//
// This revision: 8-ROW tiles (128 WGs). B-frag row = ln&7, so lane pairs
// (ln, ln+8) read IDENTICAL LDS addresses -> broadcast (m136) -> distinct
// addresses per bank halve (8->4) -> b128 data cycles should ~halve.
// MFMA count/CU unchanged (frag m=8..15 carry duplicates); state writes and
// final store predicated ln<8. 128 CUs busy instead of 64 (free).
//
// Swapped trick: S^T = W^T @ z^T (weights as MFMA A-operand). C/D layout:
// col(lane&15) = batch row m, row(q*4+r) = output col c.
// Rotated k-slice order ks=(wv+i)&7, weight frags PRE-ROTATED at load so all
// hot-loop register indices are static (R4: runtime idx -> scratch, 6.6x).

#define BS   1024
#define ZDIM 256
#define TLEN 128
#define ROWS 8          // batch rows per WG
#define ROWSTRIDE 264   // u16 units; 528 B = 16B-aligned, odd multiple of 4 units

typedef short v8s __attribute__((ext_vector_type(8)));
typedef float v4f __attribute__((ext_vector_type(4)));

static __device__ __forceinline__ ushort f2bf_rne(float x) {
    union { float f; unsigned u; } v; v.f = x;
    unsigned r = v.u + 0x7FFFu + ((v.u >> 16) & 1u);
    return (ushort)(r >> 16);
}

static __device__ __forceinline__ unsigned pk2(float a, float b) {
    union { __hip_bfloat162 h; unsigned u; } cv;
    cv.h = __float22bfloat162_rn(make_float2(a, b));
    return cv.u;
}

static __device__ __forceinline__ float fast_tanh(float x) {
    // tanh(x) = 1 - 2/(exp2(2x*log2e)+1); v_exp + v_rcp, no slow libm div
    float e = __builtin_amdgcn_exp2f(2.88539008177793f * x);
    float r = __builtin_amdgcn_rcpf(e + 1.0f);
    return 1.0f - 2.0f * r;
}

__global__ __launch_bounds__(512, 2)
void ode_mfma_kernel(const float* __restrict__ z0,
                     const float* __restrict__ t,
                     const float* __restrict__ W1,
                     const float* __restrict__ b1,
                     const float* __restrict__ W2,
                     const float* __restrict__ b2,
                     float* __restrict__ out)
{
    // state buffers, swapped layout: buf[m][c] bf16, row stride ROWSTRIDE
    __shared__ ushort zbuf[ROWS * ROWSTRIDE];
    __shared__ ushort hbuf[ROWS * ROWSTRIDE];
    __shared__ float  hsh[TLEN];            // per-step h = t[s+1]-t[s]

    const int tid  = threadIdx.x;
    const int wv   = tid >> 6;        // 0..7
    const int lane = tid & 63;
    const int q    = lane >> 4;       // 0..3
    const int ln   = lane & 15;       // frag m-col; batch row = ln&7 (dup pair)
    const int mr   = ln & 7;          // batch row within tile
    const int rowbase = blockIdx.x * ROWS;

    if (tid < TLEN - 1) hsh[tid] = t[tid + 1] - t[tid];

    // ---- one-time: weights -> registers, A-frag layout, PRE-ROTATED ----
    // wf[ct][i] holds k-slice ks=(wv+i)&7: lane has W[k=32ks+8q+j][c=32wv+16ct+ln]
    v8s w1f[2][8], w2f[2][8];
    #pragma unroll
    for (int ct = 0; ct < 2; ++ct) {
        const int c = wv * 32 + ct * 16 + ln;
        #pragma unroll
        for (int i = 0; i < 8; ++i) {
            const int ks = (wv + i) & 7;
            v8s a, b;
            #pragma unroll
            for (int j = 0; j < 8; ++j) {
                const int k = ks * 32 + q * 8 + j;
                a[j] = (short)f2bf_rne(W1[k * ZDIM + c]);
                b[j] = (short)f2bf_rne(W2[k * ZDIM + c]);
            }
            w1f[ct][i] = a;
            w2f[ct][i] = b;
        }
    }

    // biases in C'-layout: value row (c = 32wv + 16ct + 4q + r)
    v4f b1f[2], b2f[2];
    #pragma unroll
    for (int ct = 0; ct < 2; ++ct)
        #pragma unroll
        for (int r = 0; r < 4; ++r) {
            b1f[ct][r] = b1[wv * 32 + ct * 16 + q * 4 + r];
            b2f[ct][r] = b2[wv * 32 + ct * 16 + q * 4 + r];
        }

    // LDS offsets (u16 units); rdaddr[i] carries the matching slice rotation.
    // Row index is mr (=ln&7): lanes ln and ln+8 share addresses -> broadcast.
    const int rdbase = mr * ROWSTRIDE + q * 8;            // + 32*ks, b128 reads
    const int wrbase = mr * ROWSTRIDE + wv * 32 + q * 4;  // + 16*ct,  b64 writes
    int rdaddr[8];
    #pragma unroll
    for (int i = 0; i < 8; ++i)
        rdaddr[i] = rdbase + ((wv + i) & 7) * 32;

    // ---- initial state (rows duplicated into both frag halves) ----
    float zloc[2][4];   // z[m=mr][c = 32wv+16ct+4q+r], fp32
    #pragma unroll
    for (int ct = 0; ct < 2; ++ct) {
        #pragma unroll
        for (int r = 0; r < 4; ++r)
            zloc[ct][r] = z0[(rowbase + mr) * ZDIM + wv * 32 + ct * 16 + q * 4 + r];
        if (ln < 8) {
            uint2 p; p.x = pk2(zloc[ct][0], zloc[ct][1]); p.y = pk2(zloc[ct][2], zloc[ct][3]);
            *(uint2*)&zbuf[wrbase + ct * 16] = p;
        }
    }
    __syncthreads();

    float kacc[2][4];

    #pragma unroll 1
    for (int step = 0; step < TLEN - 1; ++step) {
        const float h = hsh[step];

        #pragma unroll
        for (int stage = 0; stage < 4; ++stage) {
            // ---- GEMM1: S^T = W1^T z^T + b1 (rotated slice order) ----
            v4f acc0 = b1f[0], acc1 = b1f[1];
            #pragma unroll
            for (int i = 0; i < 8; ++i) {
                const v8s zf = *(const v8s*)&zbuf[rdaddr[i]];
                acc0 = __builtin_amdgcn_mfma_f32_16x16x32_bf16(w1f[0][i], zf, acc0, 0, 0, 0);
                acc1 = __builtin_amdgcn_mfma_f32_16x16x32_bf16(w1f[1][i], zf, acc1, 0, 0, 0);
            }
            // tanh -> hbuf; write p0 before computing p1 (shorter tail)
            {
                uint2 p0;
                p0.x = pk2(fast_tanh(acc0[0]), fast_tanh(acc0[1]));
                p0.y = pk2(fast_tanh(acc0[2]), fast_tanh(acc0[3]));
                if (ln < 8) *(uint2*)&hbuf[wrbase] = p0;
                uint2 p1;
                p1.x = pk2(fast_tanh(acc1[0]), fast_tanh(acc1[1]));
                p1.y = pk2(fast_tanh(acc1[2]), fast_tanh(acc1[3]));
                if (ln < 8) *(uint2*)&hbuf[wrbase + 16] = p1;
            }
            __syncthreads();

            // ---- GEMM2: f^T = W2^T h^T + b2 (rotated slice order) ----
            v4f fv0 = b2f[0], fv1 = b2f[1];
            #pragma unroll
            for (int i = 0; i < 8; ++i) {
                const v8s hf = *(const v8s*)&hbuf[rdaddr[i]];
                fv0 = __builtin_amdgcn_mfma_f32_16x16x32_bf16(w2f[0][i], hf, fv0, 0, 0, 0);
                fv1 = __builtin_amdgcn_mfma_f32_16x16x32_bf16(w2f[1][i], hf, fv1, 0, 0, 0);
            }

            // ---- RK4 epilogue: only zn pack+write before the barrier ----
            if (stage < 3) {
                const float c = (stage == 2) ? h : 0.5f * h;
                #pragma unroll
                for (int ct = 0; ct < 2; ++ct) {
                    const v4f f = ct ? fv1 : fv0;
                    float zn[4];
                    #pragma unroll
                    for (int r = 0; r < 4; ++r) zn[r] = zloc[ct][r] + c * f[r];
                    if (ln < 8) {
                        uint2 p; p.x = pk2(zn[0], zn[1]); p.y = pk2(zn[2], zn[3]);
                        *(uint2*)&zbuf[wrbase + ct * 16] = p;
                    }
                }
                __syncthreads();
                // deferred kacc bookkeeping: overlaps next GEMM1's reads
                #pragma unroll
                for (int ct = 0; ct < 2; ++ct) {
                    const v4f f = ct ? fv1 : fv0;
                    #pragma unroll
                    for (int r = 0; r < 4; ++r) {
                        if (stage == 0) kacc[ct][r] = f[r];
                        else            kacc[ct][r] += 2.0f * f[r];
                    }
                }
            } else {
                #pragma unroll
                for (int ct = 0; ct < 2; ++ct) {
                    const v4f f = ct ? fv1 : fv0;
                    #pragma unroll
                    for (int r = 0; r < 4; ++r) {
                        kacc[ct][r] += f[r];
                        zloc[ct][r] += (h * (1.0f / 6.0f)) * kacc[ct][r];
                    }
                    if (ln < 8) {
                        uint2 p; p.x = pk2(zloc[ct][0], zloc[ct][1]);
                        p.y = pk2(zloc[ct][2], zloc[ct][3]);
                        *(uint2*)&zbuf[wrbase + ct * 16] = p;
                    }
                }
                __syncthreads();
            }
        }
    }

    // ---- final store (one-time; ln<8 lanes hold the valid rows) ----
    if (ln < 8) {
        #pragma unroll
        for (int ct = 0; ct < 2; ++ct)
            #pragma unroll
            for (int r = 0; r < 4; ++r)
                out[(rowbase + mr) * ZDIM + wv * 32 + ct * 16 + q * 4 + r] = zloc[ct][r];
    }
}

extern "C" void kernel_launch(void* const* d_in, const int* in_sizes, int n_in,
                              void* d_out, int out_size, void* d_ws, size_t ws_size,
                              hipStream_t stream) {
    const float* z0 = (const float*)d_in[0];
    const float* t  = (const float*)d_in[1];
    const float* W1 = (const float*)d_in[2];
    const float* b1 = (const float*)d_in[3];
    const float* W2 = (const float*)d_in[4];
    const float* b2 = (const float*)d_in[5];
    float* out = (float*)d_out;

    dim3 grid(BS / ROWS);  // 128 workgroups, 8 batch rows each
    dim3 block(512);       // 8 waves, 2 per SIMD
    hipLaunchKernelGGL(ode_mfma_kernel, grid, block, 0, stream,
                       z0, t, W1, b1, W2, b2, out);
}